// Round 1
// baseline (299.511 us; speedup 1.0000x reference)
//
#include <hip/hip_runtime.h>
#include <math.h>

constexpr int B = 8, C = 32, K = 5, HW = 65536;
constexpr int NCH1 = 128;   // blocks per batch, kernel 1
constexpr int NCH3 = 128;   // blocks per batch, kernel 3
// -0.5 * 32 * ln(2*pi)
constexpr double NEG_HALF_C_LOG2PI = -29.406033062549518;

// ---------------------------------------------------------------------------
// Kernel 1: per-batch Gram matrix of x = [z(32 rows); g(5 rows); ones; 0; 0]
// Gram[b][r][c] = sum_n x_r[n] * x_c[n]   (40x40, gives ZZ, gz, Sz, Sg)
// Block: 256 thr = 64 tiles (5x5) x 4 pixel-slices. LDS tile 64 px x 41 (pad).
// ---------------------------------------------------------------------------
__global__ __launch_bounds__(256) void k1_gram(const float* __restrict__ z,
                                               const float* __restrict__ g,
                                               float* __restrict__ gram) {
  __shared__ float xs[64][41];
  const int tid  = threadIdx.x;
  const int lane = tid & 63;
  const int s    = tid >> 6;          // pixel slice 0..3
  const int b    = blockIdx.x / NCH1;
  const int ch   = blockIdx.x % NCH1;
  const int t    = tid & 63;          // tile id 0..63
  const int tr   = (t >> 3) * 5;
  const int tc   = (t & 7) * 5;

  // constant rows 37 (ones), 38/39 (zero) — written once, never overwritten
  if (tid < 192) { int n = tid & 63; int r = 37 + (tid >> 6); xs[n][r] = (r == 37) ? 1.f : 0.f; }

  float acc[5][5];
#pragma unroll
  for (int i = 0; i < 5; i++)
#pragma unroll
    for (int j = 0; j < 5; j++) acc[i][j] = 0.f;

  const int PPB = HW / NCH1;   // 512 px per block
  const int NIT = PPB / 64;    // 8 iters
  for (int it = 0; it < NIT; ++it) {
    const int n0 = ch * PPB + it * 64;
    __syncthreads();
    for (int r = s; r < 37; r += 4) {   // r wave-uniform
      float val;
      if (r < 32) val = z[(b * C + r) * HW + n0 + lane];
      else        val = g[(b * K + (r - 32)) * HW + n0 + lane];
      xs[lane][r] = val;
    }
    __syncthreads();
#pragma unroll
    for (int ii = 0; ii < 16; ++ii) {
      const int p = s + 4 * ii;
      float xr[5], xc[5];
#pragma unroll
      for (int i = 0; i < 5; i++) xr[i] = xs[p][tr + i];
#pragma unroll
      for (int j = 0; j < 5; j++) xc[j] = xs[p][tc + j];
#pragma unroll
      for (int i = 0; i < 5; i++)
#pragma unroll
        for (int j = 0; j < 5; j++) acc[i][j] = fmaf(xr[i], xc[j], acc[i][j]);
    }
  }

  // reduce the 4 pixel-slice partials per tile in LDS, one atomic per element
  float* sh = &xs[0][0];
#pragma unroll
  for (int i = 0; i < 5; i++)
#pragma unroll
    for (int j = 0; j < 5; j++) {
      __syncthreads();
      sh[tid] = acc[i][j];
      __syncthreads();
      if (tid < 64) {
        float tt = sh[tid] + sh[tid + 64] + sh[tid + 128] + sh[tid + 192];
        atomicAdd(&gram[b * 1600 + (tr + i) * 40 + (tc + j)], tt);
      }
    }
}

// ---------------------------------------------------------------------------
// Kernel 2: per-(b,k) setup, fp64. mu -> cov -> chol -> A=L^-1 (packed, rows
// padded to multiple of 4 floats, zero-filled) -> v=A*mu -> const term.
// One block of 64 threads per (b,k); 40 blocks.
// ---------------------------------------------------------------------------
__global__ void k2_setup(const float* __restrict__ gram,
                         float* __restrict__ Apad,
                         float* __restrict__ vout,
                         float* __restrict__ cterm) {
  const int b = blockIdx.x / K, k = blockIdx.x % K;
  const float* G = gram + b * 1600;
  __shared__ double cov[32][33];
  __shared__ double Lm[32][33];
  __shared__ double mu[32], sz[32];
  __shared__ double red[64];
  const int tid = threadIdx.x;
  const double sg = (double)G[37 * 40 + 32 + k];

  if (tid < 32) {
    mu[tid] = (double)G[(32 + k) * 40 + tid] / (sg + 1e-6);
    sz[tid] = (double)G[37 * 40 + tid];
  }
  __syncthreads();
  if (tid == 0) {
    double t = 0; for (int c = 0; c < 32; c++) t += mu[c] * mu[c];
    red[0] = 1.0 / (1e-6 + sqrt(t));
  }
  __syncthreads();
  if (tid < 32) mu[tid] *= red[0];
  __syncthreads();
  for (int e = tid; e < 1024; e += 64) {
    int ci = e >> 5, di = e & 31;
    cov[ci][di] = (double)G[ci * 40 + di] - mu[ci] * sz[di] - mu[di] * sz[ci]
                + 65536.0 * mu[ci] * mu[di];
  }
  __syncthreads();
  if (tid < 32) { double dg = fmax(cov[tid][tid], 1e-6); cov[tid][tid] += dg; }
  __syncthreads();
  {
    double p = 0;
    for (int e = tid; e < 1024; e += 64) { int ci = e >> 5, di = e & 31; p += cov[ci][di] * cov[ci][di]; }
    red[tid] = p;
  }
  __syncthreads();
  if (tid == 0) {
    double t = 0; for (int i = 0; i < 64; i++) t += red[i];
    red[0] = 1.0 / (1e-6 + sqrt(t));
  }
  __syncthreads();
  {
    double sc = red[0];
    for (int e = tid; e < 1024; e += 64) { int ci = e >> 5, di = e & 31; cov[ci][di] *= sc; }
  }
  __syncthreads();
  // Cholesky (lower)
  for (int j = 0; j < 32; j++) {
    if (tid == 0) {
      double t = cov[j][j];
      for (int q = 0; q < j; q++) t -= Lm[j][q] * Lm[j][q];
      Lm[j][j] = sqrt(fmax(t, 1e-300));
    }
    __syncthreads();
    const int i = j + 1 + tid;
    if (i < 32) {
      double t = cov[i][j];
      for (int q = 0; q < j; q++) t -= Lm[i][q] * Lm[j][q];
      Lm[i][j] = t / Lm[j][j];
    }
    __syncthreads();
  }
  // A = L^-1 (column per thread), stored into cov's lower triangle
  if (tid < 32) {
    const int j = tid;
    for (int i = j; i < 32; i++) {
      double t = (i == j) ? 1.0 : 0.0;
      for (int q = j; q < i; q++) t -= Lm[i][q] * cov[q][j];
      cov[i][j] = t / Lm[i][i];
    }
  }
  __syncthreads();
  // packed padded write: row c occupies 4*ceil((c+1)/4) floats, zero pad
  {
    float* Ao = Apad + (b * K + k) * 576;
    int off = 0;
    for (int c = 0; c < 32; c++) {
      int len = 4 * ((c + 4) >> 2);
      for (int d = tid; d < len; d += 64)
        Ao[off + d] = (d <= c) ? (float)cov[c][d] : 0.f;
      off += len;
    }
  }
  if (tid < 32) {
    const int c = tid;
    double t = 0;
    for (int d = 0; d <= c; d++) t += cov[c][d] * mu[d];
    vout[(b * K + k) * 32 + c] = (float)t;
  }
  if (tid == 0) {
    double ld = 0; for (int j = 0; j < 32; j++) ld += log(Lm[j][j]);
    double phi = sg / 65536.0;
    cterm[b * K + k] = (float)(NEG_HALF_C_LOG2PI - ld + phi);  // -0.5*logdet = -ld
  }
}

// ---------------------------------------------------------------------------
// Kernel 3: maha + online logsumexp. 2 px/thread in registers, A/v broadcast
// from LDS (float4). Per-wave (m,s) partials via shuffle merge.
// ---------------------------------------------------------------------------
__global__ __launch_bounds__(256) void k3_maha(const float* __restrict__ z,
                                               const float* __restrict__ Apad,
                                               const float* __restrict__ vglob,
                                               float2* __restrict__ partials) {
  __shared__ __align__(16) float Ash[K * 576];
  __shared__ float vsh[K * 32];
  const int tid = threadIdx.x;
  const int b = blockIdx.x / NCH3;
  const int ch = blockIdx.x % NCH3;
  for (int i = tid; i < K * 576; i += 256) Ash[i] = Apad[b * (K * 576) + i];
  for (int i = tid; i < K * 32; i += 256) vsh[i] = vglob[b * (K * 32) + i];
  __syncthreads();

  const float* zb = z + b * C * HW;
  const int n0 = ch * 512 + tid;
  const int n1 = n0 + 256;
  float z0[32], z1[32];
#pragma unroll
  for (int c = 0; c < 32; c++) { z0[c] = zb[c * HW + n0]; z1[c] = zb[c * HW + n1]; }

#pragma unroll 1
  for (int k = 0; k < K; k++) {
    const float* Ak = &Ash[k * 576];
    const float* vk = &vsh[k * 32];
    float maha0 = 0.f, maha1 = 0.f;
    int off = 0;
#pragma unroll
    for (int c = 0; c < 32; c++) {
      float y0 = -vk[c];
      float y1 = y0;
      const int ng = (c + 4) >> 2;
#pragma unroll
      for (int q = 0; q < ng; q++) {
        const float4 a = *(const float4*)&Ak[off + 4 * q];
        y0 = fmaf(a.x, z0[4 * q + 0], y0); y0 = fmaf(a.y, z0[4 * q + 1], y0);
        y0 = fmaf(a.z, z0[4 * q + 2], y0); y0 = fmaf(a.w, z0[4 * q + 3], y0);
        y1 = fmaf(a.x, z1[4 * q + 0], y1); y1 = fmaf(a.y, z1[4 * q + 1], y1);
        y1 = fmaf(a.z, z1[4 * q + 2], y1); y1 = fmaf(a.w, z1[4 * q + 3], y1);
      }
      off += 4 * ng;
      maha0 = fmaf(y0, y0, maha0);
      maha1 = fmaf(y1, y1, maha1);
    }
    float L0 = -0.5f * maha0, L1 = -0.5f * maha1;
    float mm = fmaxf(L0, L1);
    float ss = __expf(L0 - mm) + __expf(L1 - mm);
#pragma unroll
    for (int d = 1; d < 64; d <<= 1) {
      float mo = __shfl_xor(mm, d, 64);
      float so = __shfl_xor(ss, d, 64);
      float nm = fmaxf(mm, mo);
      ss = ss * __expf(mm - nm) + so * __expf(mo - nm);
      mm = nm;
    }
    if ((tid & 63) == 0)
      partials[((b * K + k) * NCH3 + ch) * 4 + (tid >> 6)] = make_float2(mm, ss);
  }
}

// ---------------------------------------------------------------------------
// Kernel 4a: merge the 512 wave-partials per (b,k) in fp64 -> log_sum + const
// ---------------------------------------------------------------------------
__global__ void k4a_lse(const float2* __restrict__ partials,
                        const float* __restrict__ cterm,
                        float* __restrict__ lsebuf) {
  const int bk = blockIdx.x;     // 0..39
  const int lane = threadIdx.x;  // 64
  const float2* p = partials + bk * (NCH3 * 4);
  double M = -1e300, S = 0.0;
  for (int i = lane; i < NCH3 * 4; i += 64) {
    const float2 q = p[i];
    double mm = (double)q.x, ss = (double)q.y;
    double nm = fmax(M, mm);
    S = S * exp(M - nm) + ss * exp(mm - nm);
    M = nm;
  }
#pragma unroll
  for (int d = 1; d < 64; d <<= 1) {
    double mo = __shfl_xor(M, d, 64);
    double so = __shfl_xor(S, d, 64);
    double nm = fmax(M, mo);
    S = S * exp(M - nm) + so * exp(mo - nm);
    M = nm;
  }
  if (lane == 0) lsebuf[bk] = (float)(M + log(S) + (double)cterm[bk]);
}

// Kernel 4b: energy = -mean(log_sum)/hw
__global__ void k4b_final(const float* __restrict__ lsebuf, float* __restrict__ out) {
  const int lane = threadIdx.x;
  double v = (lane < 40) ? (double)lsebuf[lane] : 0.0;
#pragma unroll
  for (int d = 1; d < 64; d <<= 1) v += __shfl_xor(v, d, 64);
  if (lane == 0) out[0] = (float)(-v / (40.0 * 65536.0));
}

extern "C" void kernel_launch(void* const* d_in, const int* in_sizes, int n_in,
                              void* d_out, int out_size, void* d_ws, size_t ws_size,
                              hipStream_t stream) {
  const float* z = (const float*)d_in[0];
  const float* g = (const float*)d_in[1];
  float* out = (float*)d_out;

  float*  gram   = (float*)d_ws;                  // 8*1600 floats
  float*  Apad   = gram + B * 1600;               // 8*5*576
  float*  vv     = Apad + B * K * 576;            // 8*5*32
  float*  ct     = vv + B * K * 32;               // 40
  float2* part   = (float2*)(ct + 40);            // 40*NCH3*4 float2 (8B aligned)
  float*  lsebuf = (float*)(part + 40 * NCH3 * 4);// 40

  hipMemsetAsync(gram, 0, B * 1600 * sizeof(float), stream);
  k1_gram<<<B * NCH1, 256, 0, stream>>>(z, g, gram);
  k2_setup<<<B * K, 64, 0, stream>>>(gram, Apad, vv, ct);
  k3_maha<<<B * NCH3, 256, 0, stream>>>(z, Apad, vv, part);
  k4a_lse<<<B * K, 64, 0, stream>>>(part, ct, lsebuf);
  k4b_final<<<1, 64, 0, stream>>>(lsebuf, out);
}

// Round 2
// 275.783 us; speedup vs baseline: 1.0860x; 1.0860x over previous
//
#include <hip/hip_runtime.h>
#include <math.h>

constexpr int B = 8, C = 32, K = 5, HW = 65536;
constexpr int K1B  = 64;             // k1 blocks per batch (512 total)
constexpr int K1PX = HW / K1B;       // 1024 px per k1 block
constexpr int NIT  = K1PX / 128;     // 8 staging iterations (128 px each)
constexpr int NCH3 = 64;             // k3 blocks per batch (512 total)
constexpr int NPART = NCH3 * 4;      // lse partials per (b,k)
// -0.5 * 32 * ln(2*pi)
constexpr double NEG_HALF_C_LOG2PI = -29.406033062549518;

typedef __attribute__((ext_vector_type(8))) short bf16x8;
typedef __attribute__((ext_vector_type(4))) float f32x4;

__device__ inline unsigned short f2bf(float f) {  // RNE fp32 -> bf16
  unsigned int u = __float_as_uint(f);
  return (unsigned short)((u + 0x7fffu + ((u >> 16) & 1u)) >> 16);
}
__device__ inline float bf2f(unsigned short h) {
  return __uint_as_float(((unsigned int)h) << 16);
}

// ---------------------------------------------------------------------------
// Kernel 1: per-batch Gram of X = [z(32); g(5); ones; zero-pad] via MFMA with
// bf16 hi/lo splitting (drop lo*lo). 6 lower-triangle 16x16 tiles, K=65536.
// LDS stage: rows 0-47 hi, 48-95 lo; row stride 136 bf16 (272 B, 16B-aligned,
// worst LDS aliasing 2-way = free). Per-block partial (6*256 fp32) to global.
// ---------------------------------------------------------------------------
__global__ __launch_bounds__(256) void k1_gram(const float* __restrict__ z,
                                               const float* __restrict__ g,
                                               float* __restrict__ part) {
  __shared__ __align__(16) unsigned short xs[96 * 136];
  unsigned int* xsu = (unsigned int*)xs;
  const int tid  = threadIdx.x;
  const int lane = tid & 63;
  const int w    = tid >> 6;            // wave id = row-slice id = px chunk id
  const int b    = blockIdx.x / K1B;
  const int blk  = blockIdx.x % K1B;
  const int px0  = blk * K1PX;

  // constant rows: hi 37 (=ones), 38-47 (=0); lo 85-95 (=0). cols 0..127.
  for (int idx = tid; idx < 22 * 64; idx += 256) {
    int rr  = idx >> 6;
    int row = (rr < 11) ? (37 + rr) : (85 + rr - 11);
    xsu[row * 68 + (idx & 63)] = (row == 37) ? 0x3f803f80u : 0u;
  }

  f32x4 a00 = {0.f,0.f,0.f,0.f}, a10 = {0.f,0.f,0.f,0.f}, a11 = {0.f,0.f,0.f,0.f};
  f32x4 a20 = {0.f,0.f,0.f,0.f}, a21 = {0.f,0.f,0.f,0.f}, a22 = {0.f,0.f,0.f,0.f};

  // prefetch iter 0: thread covers rows w, w+4, ..., px pair 2*lane
  float2 pre[10];
#pragma unroll
  for (int j = 0; j < 10; ++j) {
    int r = w + 4 * j;
    if (r < 37) {
      const float* src = (r < 32) ? (z + (size_t)(b * C + r) * HW)
                                  : (g + (size_t)(b * K + (r - 32)) * HW);
      pre[j] = ((const float2*)(src + px0))[lane];
    }
  }

  const int lm = lane & 15, q = lane >> 4;
  const int co = w * 32 + q * 8;        // px column offset in the 128-px stage

  for (int it = 0; it < NIT; ++it) {
    __syncthreads();   // prior MFMA reads done before overwrite
    // convert + write staged rows (hi and lo)
#pragma unroll
    for (int j = 0; j < 10; ++j) {
      int r = w + 4 * j;
      if (r < 37) {
        unsigned short hx = f2bf(pre[j].x), hy = f2bf(pre[j].y);
        float lx = pre[j].x - bf2f(hx);
        float ly = pre[j].y - bf2f(hy);
        xsu[r * 68 + lane]        = (unsigned int)hx | ((unsigned int)hy << 16);
        xsu[(r + 48) * 68 + lane] = (unsigned int)f2bf(lx) | ((unsigned int)f2bf(ly) << 16);
      }
    }
    __syncthreads();
    // prefetch next iter (overlaps MFMA below)
    if (it + 1 < NIT) {
#pragma unroll
      for (int j = 0; j < 10; ++j) {
        int r = w + 4 * j;
        if (r < 37) {
          const float* src = (r < 32) ? (z + (size_t)(b * C + r) * HW)
                                      : (g + (size_t)(b * K + (r - 32)) * HW);
          pre[j] = ((const float2*)(src + px0 + (it + 1) * 128))[lane];
        }
      }
    }
    // fragments: row = group + (lane&15), k = quad*8+j  (A and B identical)
    bf16x8 f0h = *(const bf16x8*)&xs[(0  + lm) * 136 + co];
    bf16x8 f1h = *(const bf16x8*)&xs[(16 + lm) * 136 + co];
    bf16x8 f2h = *(const bf16x8*)&xs[(32 + lm) * 136 + co];
    bf16x8 f0l = *(const bf16x8*)&xs[(48 + lm) * 136 + co];
    bf16x8 f1l = *(const bf16x8*)&xs[(64 + lm) * 136 + co];
    bf16x8 f2l = *(const bf16x8*)&xs[(80 + lm) * 136 + co];
#define MF(d, x, y) d = __builtin_amdgcn_mfma_f32_16x16x32_bf16(x, y, d, 0, 0, 0)
    MF(a00, f0h, f0h); MF(a00, f0h, f0l); MF(a00, f0l, f0h);
    MF(a10, f1h, f0h); MF(a10, f1h, f0l); MF(a10, f1l, f0h);
    MF(a11, f1h, f1h); MF(a11, f1h, f1l); MF(a11, f1l, f1h);
    MF(a20, f2h, f0h); MF(a20, f2h, f0l); MF(a20, f2l, f0h);
    MF(a21, f2h, f1h); MF(a21, f2h, f1l); MF(a21, f2l, f1h);
    MF(a22, f2h, f2h); MF(a22, f2h, f2l); MF(a22, f2l, f2h);
#undef MF
  }

  // cross-wave reduce of the 6 tile accumulators, then one partial per block
  __syncthreads();
  float* fb = (float*)xs;   // 4 waves * 6 tiles * 4 regs * 64 lanes = 24 KB
#pragma unroll
  for (int rr = 0; rr < 4; ++rr) {
    fb[((w * 6 + 0) * 4 + rr) * 64 + lane] = a00[rr];
    fb[((w * 6 + 1) * 4 + rr) * 64 + lane] = a10[rr];
    fb[((w * 6 + 2) * 4 + rr) * 64 + lane] = a11[rr];
    fb[((w * 6 + 3) * 4 + rr) * 64 + lane] = a20[rr];
    fb[((w * 6 + 4) * 4 + rr) * 64 + lane] = a21[rr];
    fb[((w * 6 + 5) * 4 + rr) * 64 + lane] = a22[rr];
  }
  __syncthreads();
  float* po = part + (size_t)blockIdx.x * 1536;
#pragma unroll
  for (int t = 0; t < 6; ++t) {
    int sl = (tid >> 6), ln = (tid & 63);
    float v = fb[((0 * 6 + t) * 4 + sl) * 64 + ln] + fb[((1 * 6 + t) * 4 + sl) * 64 + ln]
            + fb[((2 * 6 + t) * 4 + sl) * 64 + ln] + fb[((3 * 6 + t) * 4 + sl) * 64 + ln];
    po[t * 256 + tid] = v;   // index = t*256 + reg*64 + lane
  }
}

// ---------------------------------------------------------------------------
// Kernel 1b: sum per-block partials (fp64), decode MFMA C-layout
// (col = lane&15, row = quad*4 + reg), symmetrize into gram[b][40][40].
// ---------------------------------------------------------------------------
__global__ void k1b_reduce(const float* __restrict__ part, float* __restrict__ gram) {
  const int b = blockIdx.x;        // 8
  const int tid = threadIdx.x;     // 256
  const int rr = tid >> 6, lane = tid & 63;
  const int m = (lane >> 4) * 4 + rr, n = lane & 15;
  const int TI[6] = {0, 1, 1, 2, 2, 2};
  const int TJ[6] = {0, 0, 1, 0, 1, 2};
#pragma unroll
  for (int t = 0; t < 6; ++t) {
    double s = 0.0;
    for (int blk = 0; blk < K1B; ++blk)
      s += (double)part[(size_t)(b * K1B + blk) * 1536 + t * 256 + tid];
    int gr = TI[t] * 16 + m, gc = TJ[t] * 16 + n;
    if (gr < 40 && gc < 40) {
      gram[b * 1600 + gr * 40 + gc] = (float)s;
      gram[b * 1600 + gc * 40 + gr] = (float)s;
    }
  }
}

// ---------------------------------------------------------------------------
// Kernel 2: per-(b,k) setup, fp64. mu -> cov -> chol -> A=L^-1 (packed, rows
// padded to multiple of 4 floats, zero-filled) -> v=A*mu -> const term.
// ---------------------------------------------------------------------------
__global__ void k2_setup(const float* __restrict__ gram,
                         float* __restrict__ Apad,
                         float* __restrict__ vout,
                         float* __restrict__ cterm) {
  const int b = blockIdx.x / K, k = blockIdx.x % K;
  const float* G = gram + b * 1600;
  __shared__ double cov[32][33];
  __shared__ double Lm[32][33];
  __shared__ double mu[32], sz[32];
  __shared__ double red[64];
  const int tid = threadIdx.x;
  const double sg = (double)G[37 * 40 + 32 + k];

  if (tid < 32) {
    mu[tid] = (double)G[(32 + k) * 40 + tid] / (sg + 1e-6);
    sz[tid] = (double)G[37 * 40 + tid];
  }
  __syncthreads();
  if (tid == 0) {
    double t = 0; for (int c = 0; c < 32; c++) t += mu[c] * mu[c];
    red[0] = 1.0 / (1e-6 + sqrt(t));
  }
  __syncthreads();
  if (tid < 32) mu[tid] *= red[0];
  __syncthreads();
  for (int e = tid; e < 1024; e += 64) {
    int ci = e >> 5, di = e & 31;
    cov[ci][di] = (double)G[ci * 40 + di] - mu[ci] * sz[di] - mu[di] * sz[ci]
                + 65536.0 * mu[ci] * mu[di];
  }
  __syncthreads();
  if (tid < 32) { double dg = fmax(cov[tid][tid], 1e-6); cov[tid][tid] += dg; }
  __syncthreads();
  {
    double p = 0;
    for (int e = tid; e < 1024; e += 64) { int ci = e >> 5, di = e & 31; p += cov[ci][di] * cov[ci][di]; }
    red[tid] = p;
  }
  __syncthreads();
  if (tid == 0) {
    double t = 0; for (int i = 0; i < 64; i++) t += red[i];
    red[0] = 1.0 / (1e-6 + sqrt(t));
  }
  __syncthreads();
  {
    double sc = red[0];
    for (int e = tid; e < 1024; e += 64) { int ci = e >> 5, di = e & 31; cov[ci][di] *= sc; }
  }
  __syncthreads();
  // Cholesky (lower)
  for (int j = 0; j < 32; j++) {
    if (tid == 0) {
      double t = cov[j][j];
      for (int q = 0; q < j; q++) t -= Lm[j][q] * Lm[j][q];
      Lm[j][j] = sqrt(fmax(t, 1e-300));
    }
    __syncthreads();
    const int i = j + 1 + tid;
    if (i < 32) {
      double t = cov[i][j];
      for (int q = 0; q < j; q++) t -= Lm[i][q] * Lm[j][q];
      Lm[i][j] = t / Lm[j][j];
    }
    __syncthreads();
  }
  // A = L^-1 (column per thread), stored into cov's lower triangle
  if (tid < 32) {
    const int j = tid;
    for (int i = j; i < 32; i++) {
      double t = (i == j) ? 1.0 : 0.0;
      for (int q = j; q < i; q++) t -= Lm[i][q] * cov[q][j];
      cov[i][j] = t / Lm[i][i];
    }
  }
  __syncthreads();
  // packed padded write: row c occupies 4*ceil((c+1)/4) floats, zero pad
  {
    float* Ao = Apad + (b * K + k) * 576;
    int off = 0;
    for (int c = 0; c < 32; c++) {
      int len = 4 * ((c + 4) >> 2);
      for (int d = tid; d < len; d += 64)
        Ao[off + d] = (d <= c) ? (float)cov[c][d] : 0.f;
      off += len;
    }
  }
  if (tid < 32) {
    const int c = tid;
    double t = 0;
    for (int d = 0; d <= c; d++) t += cov[c][d] * mu[d];
    vout[(b * K + k) * 32 + c] = (float)t;
  }
  if (tid == 0) {
    double ld = 0; for (int j = 0; j < 32; j++) ld += log(Lm[j][j]);
    double phi = sg / 65536.0;
    cterm[b * K + k] = (float)(NEG_HALF_C_LOG2PI - ld + phi);  // -0.5*logdet = -ld
  }
}

// ---------------------------------------------------------------------------
// Kernel 3: maha + online logsumexp. 4 px/thread (float4 z load, 128 VGPRs),
// A and v read from global with wave-uniform addresses -> scalar loads.
// ---------------------------------------------------------------------------
__global__ __launch_bounds__(256, 2) void k3_maha(const float* __restrict__ z,
                                                  const float* __restrict__ Apad,
                                                  const float* __restrict__ vglob,
                                                  float2* __restrict__ partials) {
  const int tid = threadIdx.x;
  const int b  = blockIdx.x / NCH3;
  const int ch = blockIdx.x % NCH3;
  const float* zb = z + (size_t)b * C * HW;
  const int base = ch * 1024 + tid * 4;

  float z0[32], z1[32], z2[32], z3[32];
#pragma unroll
  for (int c = 0; c < 32; ++c) {
    float4 v = *(const float4*)(zb + (size_t)c * HW + base);
    z0[c] = v.x; z1[c] = v.y; z2[c] = v.z; z3[c] = v.w;
  }

#pragma unroll 1
  for (int k = 0; k < K; ++k) {
    const float* __restrict__ Ak = Apad + (size_t)(b * K + k) * 576;   // uniform
    const float* __restrict__ vk = vglob + (size_t)(b * K + k) * 32;   // uniform
    float m0 = 0.f, m1 = 0.f, m2 = 0.f, m3 = 0.f;
    int off = 0;
#pragma unroll
    for (int c = 0; c < 32; ++c) {
      const float nv = -vk[c];
      float y0 = nv, y1 = nv, y2 = nv, y3 = nv;
      const int ng = (c + 4) >> 2;
#pragma unroll
      for (int qq = 0; qq < ng; ++qq) {
        const float4 a = *(const float4*)(Ak + off + 4 * qq);
        y0 = fmaf(a.x, z0[4*qq+0], y0); y0 = fmaf(a.y, z0[4*qq+1], y0);
        y0 = fmaf(a.z, z0[4*qq+2], y0); y0 = fmaf(a.w, z0[4*qq+3], y0);
        y1 = fmaf(a.x, z1[4*qq+0], y1); y1 = fmaf(a.y, z1[4*qq+1], y1);
        y1 = fmaf(a.z, z1[4*qq+2], y1); y1 = fmaf(a.w, z1[4*qq+3], y1);
        y2 = fmaf(a.x, z2[4*qq+0], y2); y2 = fmaf(a.y, z2[4*qq+1], y2);
        y2 = fmaf(a.z, z2[4*qq+2], y2); y2 = fmaf(a.w, z2[4*qq+3], y2);
        y3 = fmaf(a.x, z3[4*qq+0], y3); y3 = fmaf(a.y, z3[4*qq+1], y3);
        y3 = fmaf(a.z, z3[4*qq+2], y3); y3 = fmaf(a.w, z3[4*qq+3], y3);
      }
      off += 4 * ng;
      m0 = fmaf(y0, y0, m0); m1 = fmaf(y1, y1, m1);
      m2 = fmaf(y2, y2, m2); m3 = fmaf(y3, y3, m3);
    }
    const float L0 = -0.5f * m0, L1 = -0.5f * m1, L2 = -0.5f * m2, L3 = -0.5f * m3;
    float mm = fmaxf(fmaxf(L0, L1), fmaxf(L2, L3));
    float ss = __expf(L0 - mm) + __expf(L1 - mm) + __expf(L2 - mm) + __expf(L3 - mm);
#pragma unroll
    for (int d = 1; d < 64; d <<= 1) {
      float mo = __shfl_xor(mm, d, 64);
      float so = __shfl_xor(ss, d, 64);
      float nm = fmaxf(mm, mo);
      ss = ss * __expf(mm - nm) + so * __expf(mo - nm);
      mm = nm;
    }
    if ((tid & 63) == 0)
      partials[((b * K + k) * NCH3 + ch) * 4 + (tid >> 6)] = make_float2(mm, ss);
  }
}

// ---------------------------------------------------------------------------
// Kernel 4a: merge NPART wave-partials per (b,k) in fp64 -> log_sum + const
// ---------------------------------------------------------------------------
__global__ void k4a_lse(const float2* __restrict__ partials,
                        const float* __restrict__ cterm,
                        float* __restrict__ lsebuf) {
  const int bk = blockIdx.x;     // 0..39
  const int lane = threadIdx.x;  // 64
  const float2* p = partials + (size_t)bk * NPART;
  double M = -1e300, S = 0.0;
  for (int i = lane; i < NPART; i += 64) {
    const float2 q = p[i];
    double mm = (double)q.x, ss = (double)q.y;
    double nm = fmax(M, mm);
    S = S * exp(M - nm) + ss * exp(mm - nm);
    M = nm;
  }
#pragma unroll
  for (int d = 1; d < 64; d <<= 1) {
    double mo = __shfl_xor(M, d, 64);
    double so = __shfl_xor(S, d, 64);
    double nm = fmax(M, mo);
    S = S * exp(M - nm) + so * exp(mo - nm);
    M = nm;
  }
  if (lane == 0) lsebuf[bk] = (float)(M + log(S) + (double)cterm[bk]);
}

// Kernel 4b: energy = -mean(log_sum)/hw
__global__ void k4b_final(const float* __restrict__ lsebuf, float* __restrict__ out) {
  const int lane = threadIdx.x;
  double v = (lane < 40) ? (double)lsebuf[lane] : 0.0;
#pragma unroll
  for (int d = 1; d < 64; d <<= 1) v += __shfl_xor(v, d, 64);
  if (lane == 0) out[0] = (float)(-v / (40.0 * 65536.0));
}

extern "C" void kernel_launch(void* const* d_in, const int* in_sizes, int n_in,
                              void* d_out, int out_size, void* d_ws, size_t ws_size,
                              hipStream_t stream) {
  const float* z = (const float*)d_in[0];
  const float* g = (const float*)d_in[1];
  float* out = (float*)d_out;

  // workspace layout (~3.4 MB)
  float2* part3 = (float2*)d_ws;                     // 8*5*64*4 = 10240 float2
  float*  part1 = (float*)(part3 + B * K * NPART);   // 512*1536 floats
  float*  gram  = part1 + (B * K1B) * 1536;          // 8*1600
  float*  Apad  = gram + B * 1600;                   // 8*5*576
  float*  vv    = Apad + B * K * 576;                // 8*5*32
  float*  ct    = vv + B * K * 32;                   // 40
  float*  lsebuf = ct + B * K;                       // 40

  k1_gram<<<B * K1B, 256, 0, stream>>>(z, g, part1);
  k1b_reduce<<<B, 256, 0, stream>>>(part1, gram);
  k2_setup<<<B * K, 64, 0, stream>>>(gram, Apad, vv, ct);
  k3_maha<<<B * NCH3, 256, 0, stream>>>(z, Apad, vv, part3);
  k4a_lse<<<B * K, 64, 0, stream>>>(part3, ct, lsebuf);
  k4b_final<<<1, 64, 0, stream>>>(lsebuf, out);
}

// Round 3
// 212.688 us; speedup vs baseline: 1.4082x; 1.2967x over previous
//
#include <hip/hip_runtime.h>
#include <math.h>

constexpr int B = 8, C = 32, K = 5, HW = 65536;
constexpr int K1B  = 64;             // k1 blocks per batch (512 total)
constexpr int K1PX = HW / K1B;       // 1024 px per k1 block
constexpr int NIT  = K1PX / 128;     // 8 staging iterations (128 px each)
constexpr int K3PX = 256;            // px per k3 block
constexpr int K3BLK = HW / K3PX;     // 256 k3 blocks per batch (2048 total)
constexpr int NPART = K3BLK * 4;     // lse partials per (b,k) = 1024
// -0.5 * 32 * ln(2*pi)
constexpr double NEG_HALF_C_LOG2PI = -29.406033062549518;

typedef __attribute__((ext_vector_type(8))) short bf16x8;
typedef __attribute__((ext_vector_type(4))) float f32x4;

__device__ inline unsigned short f2bf(float f) {  // RNE fp32 -> bf16
  unsigned int u = __float_as_uint(f);
  return (unsigned short)((u + 0x7fffu + ((u >> 16) & 1u)) >> 16);
}
__device__ inline float bf2f(unsigned short h) {
  return __uint_as_float(((unsigned int)h) << 16);
}

// ---------------------------------------------------------------------------
// Kernel 1: per-batch Gram of X = [z(32); g(5); ones; zero-pad] via MFMA with
// bf16 hi/lo splitting (drop lo*lo). 6 lower-triangle 16x16 tiles, K=65536.
// Per-block partial (6*256 fp32) to global.
// ---------------------------------------------------------------------------
__global__ __launch_bounds__(256) void k1_gram(const float* __restrict__ z,
                                               const float* __restrict__ g,
                                               float* __restrict__ part) {
  __shared__ __align__(16) unsigned short xs[96 * 136];
  unsigned int* xsu = (unsigned int*)xs;
  const int tid  = threadIdx.x;
  const int lane = tid & 63;
  const int w    = tid >> 6;
  const int b    = blockIdx.x / K1B;
  const int blk  = blockIdx.x % K1B;
  const int px0  = blk * K1PX;

  // constant rows: hi 37 (=ones), 38-47 (=0); lo 85-95 (=0). cols 0..127.
  for (int idx = tid; idx < 22 * 64; idx += 256) {
    int rr  = idx >> 6;
    int row = (rr < 11) ? (37 + rr) : (85 + rr - 11);
    xsu[row * 68 + (idx & 63)] = (row == 37) ? 0x3f803f80u : 0u;
  }

  f32x4 a00 = {0.f,0.f,0.f,0.f}, a10 = {0.f,0.f,0.f,0.f}, a11 = {0.f,0.f,0.f,0.f};
  f32x4 a20 = {0.f,0.f,0.f,0.f}, a21 = {0.f,0.f,0.f,0.f}, a22 = {0.f,0.f,0.f,0.f};

  float2 pre[10];
#pragma unroll
  for (int j = 0; j < 10; ++j) {
    int r = w + 4 * j;
    if (r < 37) {
      const float* src = (r < 32) ? (z + (size_t)(b * C + r) * HW)
                                  : (g + (size_t)(b * K + (r - 32)) * HW);
      pre[j] = ((const float2*)(src + px0))[lane];
    }
  }

  const int lm = lane & 15, q = lane >> 4;
  const int co = w * 32 + q * 8;

  for (int it = 0; it < NIT; ++it) {
    __syncthreads();
#pragma unroll
    for (int j = 0; j < 10; ++j) {
      int r = w + 4 * j;
      if (r < 37) {
        unsigned short hx = f2bf(pre[j].x), hy = f2bf(pre[j].y);
        float lx = pre[j].x - bf2f(hx);
        float ly = pre[j].y - bf2f(hy);
        xsu[r * 68 + lane]        = (unsigned int)hx | ((unsigned int)hy << 16);
        xsu[(r + 48) * 68 + lane] = (unsigned int)f2bf(lx) | ((unsigned int)f2bf(ly) << 16);
      }
    }
    __syncthreads();
    if (it + 1 < NIT) {
#pragma unroll
      for (int j = 0; j < 10; ++j) {
        int r = w + 4 * j;
        if (r < 37) {
          const float* src = (r < 32) ? (z + (size_t)(b * C + r) * HW)
                                      : (g + (size_t)(b * K + (r - 32)) * HW);
          pre[j] = ((const float2*)(src + px0 + (it + 1) * 128))[lane];
        }
      }
    }
    bf16x8 f0h = *(const bf16x8*)&xs[(0  + lm) * 136 + co];
    bf16x8 f1h = *(const bf16x8*)&xs[(16 + lm) * 136 + co];
    bf16x8 f2h = *(const bf16x8*)&xs[(32 + lm) * 136 + co];
    bf16x8 f0l = *(const bf16x8*)&xs[(48 + lm) * 136 + co];
    bf16x8 f1l = *(const bf16x8*)&xs[(64 + lm) * 136 + co];
    bf16x8 f2l = *(const bf16x8*)&xs[(80 + lm) * 136 + co];
#define MF(d, x, y) d = __builtin_amdgcn_mfma_f32_16x16x32_bf16(x, y, d, 0, 0, 0)
    MF(a00, f0h, f0h); MF(a00, f0h, f0l); MF(a00, f0l, f0h);
    MF(a10, f1h, f0h); MF(a10, f1h, f0l); MF(a10, f1l, f0h);
    MF(a11, f1h, f1h); MF(a11, f1h, f1l); MF(a11, f1l, f1h);
    MF(a20, f2h, f0h); MF(a20, f2h, f0l); MF(a20, f2l, f0h);
    MF(a21, f2h, f1h); MF(a21, f2h, f1l); MF(a21, f2l, f1h);
    MF(a22, f2h, f2h); MF(a22, f2h, f2l); MF(a22, f2l, f2h);
#undef MF
  }

  __syncthreads();
  float* fb = (float*)xs;
#pragma unroll
  for (int rr = 0; rr < 4; ++rr) {
    fb[((w * 6 + 0) * 4 + rr) * 64 + lane] = a00[rr];
    fb[((w * 6 + 1) * 4 + rr) * 64 + lane] = a10[rr];
    fb[((w * 6 + 2) * 4 + rr) * 64 + lane] = a11[rr];
    fb[((w * 6 + 3) * 4 + rr) * 64 + lane] = a20[rr];
    fb[((w * 6 + 4) * 4 + rr) * 64 + lane] = a21[rr];
    fb[((w * 6 + 5) * 4 + rr) * 64 + lane] = a22[rr];
  }
  __syncthreads();
  float* po = part + (size_t)blockIdx.x * 1536;
#pragma unroll
  for (int t = 0; t < 6; ++t) {
    int sl = (tid >> 6), ln = (tid & 63);
    float v = fb[((0 * 6 + t) * 4 + sl) * 64 + ln] + fb[((1 * 6 + t) * 4 + sl) * 64 + ln]
            + fb[((2 * 6 + t) * 4 + sl) * 64 + ln] + fb[((3 * 6 + t) * 4 + sl) * 64 + ln];
    po[t * 256 + tid] = v;
  }
}

// ---------------------------------------------------------------------------
// Kernel 1b: sum per-block partials (fp64), decode MFMA C-layout, symmetrize.
// Grid 48 = 8 b x 6 tiles (was 8 — parallelism fix).
// ---------------------------------------------------------------------------
__global__ void k1b_reduce(const float* __restrict__ part, float* __restrict__ gram) {
  const int b = blockIdx.x / 6, t = blockIdx.x % 6;
  const int tid = threadIdx.x;     // 256
  const int rr = tid >> 6, lane = tid & 63;
  const int m = (lane >> 4) * 4 + rr, n = lane & 15;
  const int TI[6] = {0, 1, 1, 2, 2, 2};
  const int TJ[6] = {0, 0, 1, 0, 1, 2};
  double s = 0.0;
  for (int blk = 0; blk < K1B; ++blk)
    s += (double)part[(size_t)(b * K1B + blk) * 1536 + t * 256 + tid];
  int gr = TI[t] * 16 + m, gc = TJ[t] * 16 + n;
  if (gr < 40 && gc < 40) {
    gram[b * 1600 + gr * 40 + gc] = (float)s;
    gram[b * 1600 + gc * 40 + gr] = (float)s;
  }
}

// ---------------------------------------------------------------------------
// Kernel 2: per-(b,k) setup, fp64. mu -> cov -> chol -> A=L^-1 ->
// bf16 hi/lo A matrices (row-major 32x32 each) + v + const term.
// ---------------------------------------------------------------------------
__global__ void k2_setup(const float* __restrict__ gram,
                         unsigned short* __restrict__ ABout,
                         float* __restrict__ vout,
                         float* __restrict__ cterm) {
  const int b = blockIdx.x / K, k = blockIdx.x % K;
  const float* G = gram + b * 1600;
  __shared__ double cov[32][33];
  __shared__ double Lm[32][33];
  __shared__ double mu[32], sz[32];
  __shared__ double red[64];
  const int tid = threadIdx.x;
  const double sg = (double)G[37 * 40 + 32 + k];

  if (tid < 32) {
    mu[tid] = (double)G[(32 + k) * 40 + tid] / (sg + 1e-6);
    sz[tid] = (double)G[37 * 40 + tid];
  }
  __syncthreads();
  if (tid == 0) {
    double t = 0; for (int c = 0; c < 32; c++) t += mu[c] * mu[c];
    red[0] = 1.0 / (1e-6 + sqrt(t));
  }
  __syncthreads();
  if (tid < 32) mu[tid] *= red[0];
  __syncthreads();
  for (int e = tid; e < 1024; e += 64) {
    int ci = e >> 5, di = e & 31;
    cov[ci][di] = (double)G[ci * 40 + di] - mu[ci] * sz[di] - mu[di] * sz[ci]
                + 65536.0 * mu[ci] * mu[di];
  }
  __syncthreads();
  if (tid < 32) { double dg = fmax(cov[tid][tid], 1e-6); cov[tid][tid] += dg; }
  __syncthreads();
  {
    double p = 0;
    for (int e = tid; e < 1024; e += 64) { int ci = e >> 5, di = e & 31; p += cov[ci][di] * cov[ci][di]; }
    red[tid] = p;
  }
  __syncthreads();
  if (tid == 0) {
    double t = 0; for (int i = 0; i < 64; i++) t += red[i];
    red[0] = 1.0 / (1e-6 + sqrt(t));
  }
  __syncthreads();
  {
    double sc = red[0];
    for (int e = tid; e < 1024; e += 64) { int ci = e >> 5, di = e & 31; cov[ci][di] *= sc; }
  }
  __syncthreads();
  // Cholesky (lower)
  for (int j = 0; j < 32; j++) {
    if (tid == 0) {
      double t = cov[j][j];
      for (int q = 0; q < j; q++) t -= Lm[j][q] * Lm[j][q];
      Lm[j][j] = sqrt(fmax(t, 1e-300));
    }
    __syncthreads();
    const int i = j + 1 + tid;
    if (i < 32) {
      double t = cov[i][j];
      for (int q = 0; q < j; q++) t -= Lm[i][q] * Lm[j][q];
      Lm[i][j] = t / Lm[j][j];
    }
    __syncthreads();
  }
  // A = L^-1 (column per thread), stored into cov's lower triangle
  if (tid < 32) {
    const int j = tid;
    for (int i = j; i < 32; i++) {
      double t = (i == j) ? 1.0 : 0.0;
      for (int q = j; q < i; q++) t -= Lm[i][q] * cov[q][j];
      cov[i][j] = t / Lm[i][i];
    }
  }
  __syncthreads();
  // bf16 hi/lo split of A (truncation split; zeros above diagonal)
  {
    unsigned short* Ao = ABout + (size_t)(b * K + k) * 2048;
    for (int e = tid; e < 1024; e += 64) {
      int m = e >> 5, d = e & 31;
      float a = (d <= m) ? (float)cov[m][d] : 0.f;
      unsigned int u = __float_as_uint(a);
      float hf = __uint_as_float(u & 0xffff0000u);
      Ao[e] = (unsigned short)(u >> 16);
      Ao[1024 + e] = (unsigned short)(__float_as_uint(a - hf) >> 16);
    }
  }
  if (tid < 32) {
    const int c = tid;
    double t = 0;
    for (int d = 0; d <= c; d++) t += cov[c][d] * mu[d];
    vout[(b * K + k) * 32 + c] = (float)t;
  }
  if (tid == 0) {
    double ld = 0; for (int j = 0; j < 32; j++) ld += log(Lm[j][j]);
    double phi = sg / 65536.0;
    cterm[b * K + k] = (float)(NEG_HALF_C_LOG2PI - ld + phi);
  }
}

// ---------------------------------------------------------------------------
// Kernel 3: maha via MFMA. Y = A*Z - v per (b,k); maha = sum_c Y^2.
// z staged to LDS transposed (c-contiguous, 144B row stride = conflict-free
// b128), A hi/lo frags + C-init(-v) preloaded in registers, reused over
// 4 n-tiles/wave. Online lse per k, per-wave partials.
// ---------------------------------------------------------------------------
__global__ __launch_bounds__(256, 2) void k3_maha(const float* __restrict__ z,
                                                  const unsigned short* __restrict__ AB,
                                                  const float* __restrict__ vglob,
                                                  float2* __restrict__ partials) {
  __shared__ __align__(16) unsigned short zt[K3PX * 72];   // 36 KB
  const int tid  = threadIdx.x;
  const int lane = tid & 63;
  const int w    = tid >> 6;
  const int b    = blockIdx.x / K3BLK;
  const int chb  = blockIdx.x % K3BLK;
  const int px0  = chb * K3PX;

  // ---- stage: wave w handles c-group w (8 c), lane covers px 4*lane..+3 ----
  {
    const float* zb = z + (size_t)b * C * HW + px0 + 4 * lane;
    float4 rv[8];
#pragma unroll
    for (int i = 0; i < 8; ++i)
      rv[i] = *(const float4*)(zb + (size_t)(w * 8 + i) * HW);
#pragma unroll
    for (int p = 0; p < 4; ++p) {
      unsigned int hi[4], lo[4];
#pragma unroll
      for (int i = 0; i < 8; i += 2) {
        float a0 = (&rv[i].x)[p], a1 = (&rv[i + 1].x)[p];
        unsigned int u0 = __float_as_uint(a0), u1 = __float_as_uint(a1);
        float h0 = __uint_as_float(u0 & 0xffff0000u);
        float h1 = __uint_as_float(u1 & 0xffff0000u);
        hi[i >> 1] = (u0 >> 16) | (u1 & 0xffff0000u);
        lo[i >> 1] = (__float_as_uint(a0 - h0) >> 16) |
                     (__float_as_uint(a1 - h1) & 0xffff0000u);
      }
      unsigned int* row = (unsigned int*)&zt[(4 * lane + p) * 72];
      *(uint4*)(row + w * 4)      = make_uint4(hi[0], hi[1], hi[2], hi[3]);
      *(uint4*)(row + 16 + w * 4) = make_uint4(lo[0], lo[1], lo[2], lo[3]);
    }
  }
  __syncthreads();

  // ---- preload A fragments (hi/lo) and C-init (-v) for all k, mt ----
  const int lm = lane & 15, q = lane >> 4;
  bf16x8 Ah[K][2], Al[K][2];
  f32x4 Ci[K][2];
#pragma unroll
  for (int k = 0; k < K; ++k) {
    const unsigned short* Abase = AB + (size_t)(b * K + k) * 2048;
    const float* vb = vglob + (size_t)(b * K + k) * 32;
#pragma unroll
    for (int mt = 0; mt < 2; ++mt) {
      const int m = mt * 16 + lm;
      Ah[k][mt] = *(const bf16x8*)(Abase + m * 32 + q * 8);
      Al[k][mt] = *(const bf16x8*)(Abase + 1024 + m * 32 + q * 8);
#pragma unroll
      for (int r = 0; r < 4; ++r)
        Ci[k][mt][r] = -vb[mt * 16 + q * 4 + r];
    }
  }

  float mm[K], ss[K];
#pragma unroll
  for (int k = 0; k < K; ++k) { mm[k] = -1e30f; ss[k] = 0.f; }

#pragma unroll
  for (int nt = 0; nt < 4; ++nt) {
    const int px = w * 64 + nt * 16 + lm;
    bf16x8 zh = *(const bf16x8*)&zt[px * 72 + q * 8];
    bf16x8 zl = *(const bf16x8*)&zt[px * 72 + 32 + q * 8];
#pragma unroll
    for (int k = 0; k < K; ++k) {
      float acc = 0.f;
#pragma unroll
      for (int mt = 0; mt < 2; ++mt) {
        f32x4 y = Ci[k][mt];
        y = __builtin_amdgcn_mfma_f32_16x16x32_bf16(Ah[k][mt], zh, y, 0, 0, 0);
        y = __builtin_amdgcn_mfma_f32_16x16x32_bf16(Ah[k][mt], zl, y, 0, 0, 0);
        y = __builtin_amdgcn_mfma_f32_16x16x32_bf16(Al[k][mt], zh, y, 0, 0, 0);
#pragma unroll
        for (int r = 0; r < 4; ++r) acc = fmaf(y[r], y[r], acc);
      }
      acc += __shfl_xor(acc, 16, 64);   // sum over quads -> full 32-row maha
      acc += __shfl_xor(acc, 32, 64);
      const float L = -0.5f * acc;
      const float nm = fmaxf(mm[k], L);
      ss[k] = ss[k] * __expf(mm[k] - nm) + __expf(L - nm);
      mm[k] = nm;
    }
  }
  // wave lse reduce within 16-px groups (quads hold identical copies)
#pragma unroll
  for (int k = 0; k < K; ++k) {
#pragma unroll
    for (int d = 1; d < 16; d <<= 1) {
      float mo = __shfl_xor(mm[k], d, 64);
      float so = __shfl_xor(ss[k], d, 64);
      float nm = fmaxf(mm[k], mo);
      ss[k] = ss[k] * __expf(mm[k] - nm) + so * __expf(mo - nm);
      mm[k] = nm;
    }
    if (lane == 0)
      partials[((size_t)(b * K + k) * K3BLK + chb) * 4 + w] = make_float2(mm[k], ss[k]);
  }
}

// ---------------------------------------------------------------------------
// Kernel 4a: merge NPART wave-partials per (b,k) in fp64 -> log_sum + const
// ---------------------------------------------------------------------------
__global__ void k4a_lse(const float2* __restrict__ partials,
                        const float* __restrict__ cterm,
                        float* __restrict__ lsebuf) {
  const int bk = blockIdx.x;     // 0..39
  const int lane = threadIdx.x;  // 64
  const float2* p = partials + (size_t)bk * NPART;
  double M = -1e300, S = 0.0;
  for (int i = lane; i < NPART; i += 64) {
    const float2 qq = p[i];
    double mm = (double)qq.x, ss = (double)qq.y;
    double nm = fmax(M, mm);
    S = S * exp(M - nm) + ss * exp(mm - nm);
    M = nm;
  }
#pragma unroll
  for (int d = 1; d < 64; d <<= 1) {
    double mo = __shfl_xor(M, d, 64);
    double so = __shfl_xor(S, d, 64);
    double nm = fmax(M, mo);
    S = S * exp(M - nm) + so * exp(mo - nm);
    M = nm;
  }
  if (lane == 0) lsebuf[bk] = (float)(M + log(S) + (double)cterm[bk]);
}

// Kernel 4b: energy = -mean(log_sum)/hw
__global__ void k4b_final(const float* __restrict__ lsebuf, float* __restrict__ out) {
  const int lane = threadIdx.x;
  double v = (lane < 40) ? (double)lsebuf[lane] : 0.0;
#pragma unroll
  for (int d = 1; d < 64; d <<= 1) v += __shfl_xor(v, d, 64);
  if (lane == 0) out[0] = (float)(-v / (40.0 * 65536.0));
}

extern "C" void kernel_launch(void* const* d_in, const int* in_sizes, int n_in,
                              void* d_out, int out_size, void* d_ws, size_t ws_size,
                              hipStream_t stream) {
  const float* z = (const float*)d_in[0];
  const float* g = (const float*)d_in[1];
  float* out = (float*)d_out;

  // workspace layout (~3.7 MB)
  float2* part3 = (float2*)d_ws;                        // 40*1024 float2
  float*  part1 = (float*)(part3 + 40 * NPART);         // 512*1536 floats
  float*  gram  = part1 + (B * K1B) * 1536;             // 8*1600
  float*  vv    = gram + B * 1600;                      // 8*5*32
  float*  ct    = vv + B * K * 32;                      // 40
  float*  lsebuf = ct + B * K;                          // 40
  unsigned short* AB = (unsigned short*)(lsebuf + 40);  // 40*2048 shorts

  k1_gram<<<B * K1B, 256, 0, stream>>>(z, g, part1);
  k1b_reduce<<<B * 6, 256, 0, stream>>>(part1, gram);
  k2_setup<<<B * K, 64, 0, stream>>>(gram, AB, vv, ct);
  k3_maha<<<B * K3BLK, 256, 0, stream>>>(z, AB, vv, part3);
  k4a_lse<<<B * K, 64, 0, stream>>>(part3, ct, lsebuf);
  k4b_final<<<1, 64, 0, stream>>>(lsebuf, out);
}

// Round 4
// 171.778 us; speedup vs baseline: 1.7436x; 1.2382x over previous
//
#include <hip/hip_runtime.h>
#include <math.h>

constexpr int B = 8, C = 32, K = 5, HW = 65536;
constexpr int K1B  = 64;             // k1 blocks per batch (512 total)
constexpr int K1PX = HW / K1B;       // 1024 px per k1 block
constexpr int NIT  = K1PX / 128;     // 8 staging iterations (128 px each)
constexpr int K3PX = 256;            // px per k3 block
constexpr int K3BLK = HW / K3PX;     // 256 k3 blocks per batch (2048 total)
constexpr int NPART = K3BLK * 4;     // lse partials per (b,k) = 1024
constexpr float NEG_HALF_C_LOG2PI_F = -29.406033062549518f;

typedef __attribute__((ext_vector_type(8))) short bf16x8;
typedef __attribute__((ext_vector_type(4))) float f32x4;

__device__ inline unsigned short f2bf(float f) {  // RNE fp32 -> bf16
  unsigned int u = __float_as_uint(f);
  return (unsigned short)((u + 0x7fffu + ((u >> 16) & 1u)) >> 16);
}
__device__ inline float bf2f(unsigned short h) {
  return __uint_as_float(((unsigned int)h) << 16);
}

// ---------------------------------------------------------------------------
// Kernel 1: per-batch Gram of X = [z(32); g(5); ones; zero-pad] via MFMA with
// bf16 hi/lo splitting (drop lo*lo). 6 lower-triangle 16x16 tiles, K=65536.
// Per-block partial (6*256 fp32) to global.
// ---------------------------------------------------------------------------
__global__ __launch_bounds__(256) void k1_gram(const float* __restrict__ z,
                                               const float* __restrict__ g,
                                               float* __restrict__ part) {
  __shared__ __align__(16) unsigned short xs[96 * 136];
  unsigned int* xsu = (unsigned int*)xs;
  const int tid  = threadIdx.x;
  const int lane = tid & 63;
  const int w    = tid >> 6;
  const int b    = blockIdx.x / K1B;
  const int blk  = blockIdx.x % K1B;
  const int px0  = blk * K1PX;

  // constant rows: hi 37 (=ones), 38-47 (=0); lo 85-95 (=0). cols 0..127.
  for (int idx = tid; idx < 22 * 64; idx += 256) {
    int rr  = idx >> 6;
    int row = (rr < 11) ? (37 + rr) : (85 + rr - 11);
    xsu[row * 68 + (idx & 63)] = (row == 37) ? 0x3f803f80u : 0u;
  }

  f32x4 a00 = {0.f,0.f,0.f,0.f}, a10 = {0.f,0.f,0.f,0.f}, a11 = {0.f,0.f,0.f,0.f};
  f32x4 a20 = {0.f,0.f,0.f,0.f}, a21 = {0.f,0.f,0.f,0.f}, a22 = {0.f,0.f,0.f,0.f};

  float2 pre[10];
#pragma unroll
  for (int j = 0; j < 10; ++j) {
    int r = w + 4 * j;
    if (r < 37) {
      const float* src = (r < 32) ? (z + (size_t)(b * C + r) * HW)
                                  : (g + (size_t)(b * K + (r - 32)) * HW);
      pre[j] = ((const float2*)(src + px0))[lane];
    }
  }

  const int lm = lane & 15, q = lane >> 4;
  const int co = w * 32 + q * 8;

  for (int it = 0; it < NIT; ++it) {
    __syncthreads();
#pragma unroll
    for (int j = 0; j < 10; ++j) {
      int r = w + 4 * j;
      if (r < 37) {
        unsigned short hx = f2bf(pre[j].x), hy = f2bf(pre[j].y);
        float lx = pre[j].x - bf2f(hx);
        float ly = pre[j].y - bf2f(hy);
        xsu[r * 68 + lane]        = (unsigned int)hx | ((unsigned int)hy << 16);
        xsu[(r + 48) * 68 + lane] = (unsigned int)f2bf(lx) | ((unsigned int)f2bf(ly) << 16);
      }
    }
    __syncthreads();
    if (it + 1 < NIT) {
#pragma unroll
      for (int j = 0; j < 10; ++j) {
        int r = w + 4 * j;
        if (r < 37) {
          const float* src = (r < 32) ? (z + (size_t)(b * C + r) * HW)
                                      : (g + (size_t)(b * K + (r - 32)) * HW);
          pre[j] = ((const float2*)(src + px0 + (it + 1) * 128))[lane];
        }
      }
    }
    bf16x8 f0h = *(const bf16x8*)&xs[(0  + lm) * 136 + co];
    bf16x8 f1h = *(const bf16x8*)&xs[(16 + lm) * 136 + co];
    bf16x8 f2h = *(const bf16x8*)&xs[(32 + lm) * 136 + co];
    bf16x8 f0l = *(const bf16x8*)&xs[(48 + lm) * 136 + co];
    bf16x8 f1l = *(const bf16x8*)&xs[(64 + lm) * 136 + co];
    bf16x8 f2l = *(const bf16x8*)&xs[(80 + lm) * 136 + co];
#define MF(d, x, y) d = __builtin_amdgcn_mfma_f32_16x16x32_bf16(x, y, d, 0, 0, 0)
    MF(a00, f0h, f0h); MF(a00, f0h, f0l); MF(a00, f0l, f0h);
    MF(a10, f1h, f0h); MF(a10, f1h, f0l); MF(a10, f1l, f0h);
    MF(a11, f1h, f1h); MF(a11, f1h, f1l); MF(a11, f1l, f1h);
    MF(a20, f2h, f0h); MF(a20, f2h, f0l); MF(a20, f2l, f0h);
    MF(a21, f2h, f1h); MF(a21, f2h, f1l); MF(a21, f2l, f1h);
    MF(a22, f2h, f2h); MF(a22, f2h, f2l); MF(a22, f2l, f2h);
#undef MF
  }

  __syncthreads();
  float* fb = (float*)xs;
#pragma unroll
  for (int rr = 0; rr < 4; ++rr) {
    fb[((w * 6 + 0) * 4 + rr) * 64 + lane] = a00[rr];
    fb[((w * 6 + 1) * 4 + rr) * 64 + lane] = a10[rr];
    fb[((w * 6 + 2) * 4 + rr) * 64 + lane] = a11[rr];
    fb[((w * 6 + 3) * 4 + rr) * 64 + lane] = a20[rr];
    fb[((w * 6 + 4) * 4 + rr) * 64 + lane] = a21[rr];
    fb[((w * 6 + 5) * 4 + rr) * 64 + lane] = a22[rr];
  }
  __syncthreads();
  float* po = part + (size_t)blockIdx.x * 1536;
#pragma unroll
  for (int t = 0; t < 6; ++t) {
    int sl = (tid >> 6), ln = (tid & 63);
    float v = fb[((0 * 6 + t) * 4 + sl) * 64 + ln] + fb[((1 * 6 + t) * 4 + sl) * 64 + ln]
            + fb[((2 * 6 + t) * 4 + sl) * 64 + ln] + fb[((3 * 6 + t) * 4 + sl) * 64 + ln];
    po[t * 256 + tid] = v;
  }
}

// ---------------------------------------------------------------------------
// Kernel 1b: sum per-block partials (fp64 accum, 8-way load ILP), decode MFMA
// C-layout, symmetrize. Grid 48 = 8 b x 6 tiles.
// ---------------------------------------------------------------------------
__global__ void k1b_reduce(const float* __restrict__ part, float* __restrict__ gram) {
  const int b = blockIdx.x / 6, t = blockIdx.x % 6;
  const int tid = threadIdx.x;     // 256
  const int rr = tid >> 6, lane = tid & 63;
  const int m = (lane >> 4) * 4 + rr, n = lane & 15;
  const int TI[6] = {0, 1, 1, 2, 2, 2};
  const int TJ[6] = {0, 0, 1, 0, 1, 2};
  double s = 0.0;
#pragma unroll 8
  for (int blk = 0; blk < K1B; ++blk)
    s += (double)part[(size_t)(b * K1B + blk) * 1536 + t * 256 + tid];
  int gr = TI[t] * 16 + m, gc = TJ[t] * 16 + n;
  if (gr < 40 && gc < 40) {
    gram[b * 1600 + gr * 40 + gc] = (float)s;
    gram[b * 1600 + gc * 40 + gr] = (float)s;
  }
}

// ---------------------------------------------------------------------------
// Kernel 2: per-(b,k) setup, wave-parallel fp32 in registers. Full symmetric
// matrix column-per-lane (symmetry => L[r][j] = col[j]*s is a static register
// read). Right-looking Cholesky + unrolled forward-substitution inverse via
// v_readlane broadcasts; no LDS / barriers in the dependency chain.
// ---------------------------------------------------------------------------
__global__ __launch_bounds__(64) void k2_setup(const float* __restrict__ gram,
                                               unsigned short* __restrict__ ABout,
                                               float* __restrict__ vout,
                                               float* __restrict__ cterm) {
  const int b = blockIdx.x / K, k = blockIdx.x % K;
  const float* G = gram + b * 1600;
  const int lane = threadIdx.x;        // 0..63; lanes 32-63 mirror 0-31
  const int j32 = lane & 31;
  __shared__ float Amat[32][33];
  __shared__ float mus[32];

  const float sg = G[37 * 40 + 32 + k];
  float muj = G[(32 + k) * 40 + j32] / (sg + 1e-6f);
  const float szj = G[37 * 40 + j32];
  // l2-normalize mu (reduce over lanes 0..31; xor<32 stays in-half)
  float nrm = muj * muj;
#pragma unroll
  for (int d = 1; d < 32; d <<= 1) nrm += __shfl_xor(nrm, d, 64);
  muj *= 1.f / (1e-6f + sqrtf(nrm));
  if (lane < 32) mus[lane] = muj;

  // build full symmetric cov column j=lane, diag-doubled
  float col[32];
#pragma unroll
  for (int i = 0; i < 32; ++i) {
    const float mu_i = __shfl(muj, i, 64);
    const float sz_i = __shfl(szj, i, 64);
    float cv = G[i * 40 + j32] - mu_i * szj - muj * sz_i + 65536.f * mu_i * muj;
    if (i == lane) cv += fmaxf(cv, 1e-6f);
    col[i] = cv;
  }
  // Frobenius normalize
  float fs = 0.f;
#pragma unroll
  for (int i = 0; i < 32; ++i) fs = fmaf(col[i], col[i], fs);
#pragma unroll
  for (int d = 1; d < 32; d <<= 1) fs += __shfl_xor(fs, d, 64);
  const float fsc = 1.f / (1e-6f + sqrtf(fs));
#pragma unroll
  for (int i = 0; i < 32; ++i) col[i] *= fsc;

  // Cholesky, right-looking; capture own step's s and d
  float sown = 0.f, dcap = 1.f;
#pragma unroll
  for (int j = 0; j < 32; ++j) {
    float dd = __shfl(col[j], j, 64);
    dd = fmaxf(dd, 1e-30f);
    const float s = 1.f / sqrtf(dd);
    if (lane == j) { sown = s; dcap = dd; }
    const float f = (lane > j) ? col[j] * s : 0.f;
#pragma unroll
    for (int i = j + 1; i < 32; ++i) {
      const float cji = __shfl(col[i], j, 64) * s;
      col[i] = fmaf(-cji, f, col[i]);
    }
  }

  // Lc[i] = L[i][lane] (valid for i >= lane)
  float Lc[32];
#pragma unroll
  for (int i = 0; i < 32; ++i) Lc[i] = col[i] * sown;

  // x = column 'lane' of A = L^{-1} (x[i]=0 for i<lane falls out naturally)
  float x[32];
#pragma unroll
  for (int i = 0; i < 32; ++i) {
    float t0 = (lane == i) ? 1.f : 0.f, t1 = 0.f, t2 = 0.f, t3 = 0.f;
#pragma unroll
    for (int qq = 0; qq < i; ++qq) {
      const float lq = __shfl(Lc[i], qq, 64);
      const float p = lq * x[qq];
      if ((qq & 3) == 0) t0 -= p;
      else if ((qq & 3) == 1) t1 -= p;
      else if ((qq & 3) == 2) t2 -= p;
      else t3 -= p;
    }
    const float Lii = __shfl(Lc[i], i, 64);
    x[i] = ((t0 + t1) + (t2 + t3)) / Lii;
  }

  if (lane < 32) {
#pragma unroll
    for (int i = 0; i < 32; ++i) Amat[i][lane] = x[i];
  }
  __syncthreads();

  // v = A * mu (row 'lane'); A strictly lower+diag
  if (lane < 32) {
    float t = 0.f;
    for (int d2 = 0; d2 <= lane; ++d2) t = fmaf(Amat[lane][d2], mus[d2], t);
    vout[(b * K + k) * 32 + lane] = t;
  }

  // cterm = -0.5*c*log2pi - 0.5*logdet + phi ; logdet = sum_j log(d_j)
  float lg = 0.5f * logf(dcap);        // lanes>=32: dcap==1 -> 0
#pragma unroll
  for (int d = 1; d < 32; d <<= 1) lg += __shfl_xor(lg, d, 64);
  if (lane == 0)
    cterm[b * K + k] = NEG_HALF_C_LOG2PI_F - lg + sg / 65536.f;

  // bf16 hi/lo split of A (row-major 32x32 each)
  unsigned short* Ao = ABout + (size_t)(b * K + k) * 2048;
#pragma unroll
  for (int e = lane; e < 1024; e += 64) {
    const int m = e >> 5, d2 = e & 31;
    const float a = Amat[m][d2];
    const unsigned int u = __float_as_uint(a);
    const float hf = __uint_as_float(u & 0xffff0000u);
    Ao[e] = (unsigned short)(u >> 16);
    Ao[1024 + e] = (unsigned short)(__float_as_uint(a - hf) >> 16);
  }
}

// ---------------------------------------------------------------------------
// Kernel 3: maha via MFMA. Y = A*Z - v per (b,k); maha = sum_c Y^2.
// ---------------------------------------------------------------------------
__global__ __launch_bounds__(256, 2) void k3_maha(const float* __restrict__ z,
                                                  const unsigned short* __restrict__ AB,
                                                  const float* __restrict__ vglob,
                                                  float2* __restrict__ partials) {
  __shared__ __align__(16) unsigned short zt[K3PX * 72];   // 36 KB
  const int tid  = threadIdx.x;
  const int lane = tid & 63;
  const int w    = tid >> 6;
  const int b    = blockIdx.x / K3BLK;
  const int chb  = blockIdx.x % K3BLK;
  const int px0  = chb * K3PX;

  // ---- stage: wave w handles c-group w (8 c), lane covers px 4*lane..+3 ----
  {
    const float* zb = z + (size_t)b * C * HW + px0 + 4 * lane;
    float4 rv[8];
#pragma unroll
    for (int i = 0; i < 8; ++i)
      rv[i] = *(const float4*)(zb + (size_t)(w * 8 + i) * HW);
#pragma unroll
    for (int p = 0; p < 4; ++p) {
      unsigned int hi[4], lo[4];
#pragma unroll
      for (int i = 0; i < 8; i += 2) {
        float a0 = (&rv[i].x)[p], a1 = (&rv[i + 1].x)[p];
        unsigned int u0 = __float_as_uint(a0), u1 = __float_as_uint(a1);
        float h0 = __uint_as_float(u0 & 0xffff0000u);
        float h1 = __uint_as_float(u1 & 0xffff0000u);
        hi[i >> 1] = (u0 >> 16) | (u1 & 0xffff0000u);
        lo[i >> 1] = (__float_as_uint(a0 - h0) >> 16) |
                     (__float_as_uint(a1 - h1) & 0xffff0000u);
      }
      unsigned int* row = (unsigned int*)&zt[(4 * lane + p) * 72];
      *(uint4*)(row + w * 4)      = make_uint4(hi[0], hi[1], hi[2], hi[3]);
      *(uint4*)(row + 16 + w * 4) = make_uint4(lo[0], lo[1], lo[2], lo[3]);
    }
  }
  __syncthreads();

  // ---- preload A fragments (hi/lo) and C-init (-v) for all k, mt ----
  const int lm = lane & 15, q = lane >> 4;
  bf16x8 Ah[K][2], Al[K][2];
  f32x4 Ci[K][2];
#pragma unroll
  for (int k = 0; k < K; ++k) {
    const unsigned short* Abase = AB + (size_t)(b * K + k) * 2048;
    const float* vb = vglob + (size_t)(b * K + k) * 32;
#pragma unroll
    for (int mt = 0; mt < 2; ++mt) {
      const int m = mt * 16 + lm;
      Ah[k][mt] = *(const bf16x8*)(Abase + m * 32 + q * 8);
      Al[k][mt] = *(const bf16x8*)(Abase + 1024 + m * 32 + q * 8);
#pragma unroll
      for (int r = 0; r < 4; ++r)
        Ci[k][mt][r] = -vb[mt * 16 + q * 4 + r];
    }
  }

  float mm[K], ss[K];
#pragma unroll
  for (int k = 0; k < K; ++k) { mm[k] = -1e30f; ss[k] = 0.f; }

#pragma unroll
  for (int nt = 0; nt < 4; ++nt) {
    const int px = w * 64 + nt * 16 + lm;
    bf16x8 zh = *(const bf16x8*)&zt[px * 72 + q * 8];
    bf16x8 zl = *(const bf16x8*)&zt[px * 72 + 32 + q * 8];
#pragma unroll
    for (int k = 0; k < K; ++k) {
      float acc = 0.f;
#pragma unroll
      for (int mt = 0; mt < 2; ++mt) {
        f32x4 y = Ci[k][mt];
        y = __builtin_amdgcn_mfma_f32_16x16x32_bf16(Ah[k][mt], zh, y, 0, 0, 0);
        y = __builtin_amdgcn_mfma_f32_16x16x32_bf16(Ah[k][mt], zl, y, 0, 0, 0);
        y = __builtin_amdgcn_mfma_f32_16x16x32_bf16(Al[k][mt], zh, y, 0, 0, 0);
#pragma unroll
        for (int r = 0; r < 4; ++r) acc = fmaf(y[r], y[r], acc);
      }
      acc += __shfl_xor(acc, 16, 64);
      acc += __shfl_xor(acc, 32, 64);
      const float L = -0.5f * acc;
      const float nm = fmaxf(mm[k], L);
      ss[k] = ss[k] * __expf(mm[k] - nm) + __expf(L - nm);
      mm[k] = nm;
    }
  }
#pragma unroll
  for (int k = 0; k < K; ++k) {
#pragma unroll
    for (int d = 1; d < 16; d <<= 1) {
      float mo = __shfl_xor(mm[k], d, 64);
      float so = __shfl_xor(ss[k], d, 64);
      float nm = fmaxf(mm[k], mo);
      ss[k] = ss[k] * __expf(mm[k] - nm) + so * __expf(mo - nm);
      mm[k] = nm;
    }
    if (lane == 0)
      partials[((size_t)(b * K + k) * K3BLK + chb) * 4 + w] = make_float2(mm[k], ss[k]);
  }
}

// ---------------------------------------------------------------------------
// Kernel 4a: merge NPART wave-partials per (b,k), fp32 expf -> log_sum + const
// ---------------------------------------------------------------------------
__global__ void k4a_lse(const float2* __restrict__ partials,
                        const float* __restrict__ cterm,
                        float* __restrict__ lsebuf) {
  const int bk = blockIdx.x;     // 0..39
  const int lane = threadIdx.x;  // 64
  const float2* p = partials + (size_t)bk * NPART;
  float M = -1e30f, S = 0.f;
#pragma unroll 4
  for (int i = lane; i < NPART; i += 64) {
    const float2 qq = p[i];
    const float nm = fmaxf(M, qq.x);
    S = S * __expf(M - nm) + qq.y * __expf(qq.x - nm);
    M = nm;
  }
#pragma unroll
  for (int d = 1; d < 64; d <<= 1) {
    const float mo = __shfl_xor(M, d, 64);
    const float so = __shfl_xor(S, d, 64);
    const float nm = fmaxf(M, mo);
    S = S * __expf(M - nm) + so * __expf(mo - nm);
    M = nm;
  }
  if (lane == 0) lsebuf[bk] = M + logf(S) + cterm[bk];
}

// Kernel 4b: energy = -mean(log_sum)/hw
__global__ void k4b_final(const float* __restrict__ lsebuf, float* __restrict__ out) {
  const int lane = threadIdx.x;
  double v = (lane < 40) ? (double)lsebuf[lane] : 0.0;
#pragma unroll
  for (int d = 1; d < 64; d <<= 1) v += __shfl_xor(v, d, 64);
  if (lane == 0) out[0] = (float)(-v / (40.0 * 65536.0));
}

extern "C" void kernel_launch(void* const* d_in, const int* in_sizes, int n_in,
                              void* d_out, int out_size, void* d_ws, size_t ws_size,
                              hipStream_t stream) {
  const float* z = (const float*)d_in[0];
  const float* g = (const float*)d_in[1];
  float* out = (float*)d_out;

  // workspace layout (~3.7 MB)
  float2* part3 = (float2*)d_ws;                        // 40*1024 float2
  float*  part1 = (float*)(part3 + 40 * NPART);         // 512*1536 floats
  float*  gram  = part1 + (B * K1B) * 1536;             // 8*1600
  float*  vv    = gram + B * 1600;                      // 8*5*32
  float*  ct    = vv + B * K * 32;                      // 40
  float*  lsebuf = ct + B * K;                          // 40
  unsigned short* AB = (unsigned short*)(lsebuf + 40);  // 40*2048 shorts

  k1_gram<<<B * K1B, 256, 0, stream>>>(z, g, part1);
  k1b_reduce<<<B * 6, 256, 0, stream>>>(part1, gram);
  k2_setup<<<B * K, 64, 0, stream>>>(gram, AB, vv, ct);
  k3_maha<<<B * K3BLK, 256, 0, stream>>>(z, AB, vv, part3);
  k4a_lse<<<B * K, 64, 0, stream>>>(part3, ct, lsebuf);
  k4b_final<<<1, 64, 0, stream>>>(lsebuf, out);
}